// Round 1
// baseline (2778.920 us; speedup 1.0000x reference)
//
#include <hip/hip_runtime.h>
#include <stdint.h>

#define DEVFN static __device__ __forceinline__

constexpr int B = 2048;
constexpr int DIN = 768;
constexpr int D = 32768;
constexpr int NDI = B * D;                 // 67,108,864
constexpr unsigned TOPK_TOTAL = 65536u;    // 32 * B
constexpr int TOPK_AUX = 512;
constexpr int ROWCAP = 512;
constexpr int TIECAP = 4096;
constexpr int DCAP = 8192;

// ---------------- workspace layout (bytes) ----------------
constexpr size_t OFF_HIST1 = 0;
constexpr size_t OFF_HIST2 = 8192;
constexpr size_t OFF_HIST3 = 16384;
constexpr size_t OFF_SCALU = 24576;   // u32[64]
constexpr size_t OFF_SCALD = 24832;   // double[32]
constexpr size_t OFF_ROWCNT = 25088;  // u32[B]
constexpr size_t OFF_COLACT = 33280;  // u32[D]
constexpr size_t OFF_AUXCNT = 164352; // u32[B]
constexpr size_t ZERO_BYTES = 172544; // everything above zeroed each launch
constexpr size_t OFF_XN   = ZERO_BYTES;
constexpr size_t OFF_XNC  = OFF_XN  + (size_t)B * DIN * 4;
constexpr size_t OFF_RES  = OFF_XNC + (size_t)B * DIN * 4;
constexpr size_t OFF_RMEAN= OFF_RES + (size_t)B * DIN * 4;
constexpr size_t OFF_RSTD = OFF_RMEAN + (size_t)B * 4;
constexpr size_t OFF_TIE  = OFF_RSTD + (size_t)B * 4;
constexpr size_t OFF_DEAD = OFF_TIE + (size_t)TIECAP * 4;
constexpr size_t OFF_RLC  = OFF_DEAD + (size_t)D * 4;
constexpr size_t OFF_RLV  = OFF_RLC + (size_t)B * ROWCAP * 4;
constexpr size_t OFF_AXC  = OFF_RLV + (size_t)B * ROWCAP * 4;
constexpr size_t OFF_AXV  = OFF_AXC + (size_t)B * TOPK_AUX * 4;

// scalU: 0 b1, 1 cntgt1, 2 b2, 3 cntgt2, 4 cutoff_bits, 5 cntgt_final,
//        6 need_ties, 7 tie_thr(i32), 8 tie_count, 9 l0_count, 10 n_dead, 11 num_dead_feat
// scalD: 0 l1_sum, 1 sum_xn, 2 sumsq_xn, 3 sq0, 4..8 group_sq[5], 9 aux_sq, 10 aux_abs

DEVFN float bsumf(float v, float* red) {
  int t = threadIdx.x;
  red[t] = v; __syncthreads();
  for (int o = 128; o > 0; o >>= 1) { if (t < o) red[t] += red[t + o]; __syncthreads(); }
  float r = red[0]; __syncthreads();
  return r;
}
DEVFN unsigned bsumu(unsigned v, unsigned* red) {
  int t = threadIdx.x;
  red[t] = v; __syncthreads();
  for (int o = 128; o > 0; o >>= 1) { if (t < o) red[t] += red[t + o]; __syncthreads(); }
  unsigned r = red[0]; __syncthreads();
  return r;
}

// Find bin (scanning from the top / largest values) where cumulative count reaches K.
// nb must be a multiple of 256. Writes *s_b (bin) and *s_cnt (count strictly above bin).
DEVFN void findBin(const unsigned* hist, int nb, unsigned K, unsigned base,
                   unsigned* sscan, int* s_b, unsigned* s_cnt)
{
  int t = threadIdx.x;
  int chunk = nb >> 8;
  int hi = nb - 1 - t * chunk;
  unsigned p = 0;
  for (int k = 0; k < chunk; ++k) p += hist[hi - k];
  sscan[t] = p; __syncthreads();
  for (int o = 1; o < 256; o <<= 1) {
    unsigned xx = (t >= o) ? sscan[t - o] : 0u; __syncthreads();
    sscan[t] += xx; __syncthreads();
  }
  unsigned incl = sscan[t], excl = incl - p;
  unsigned cum = base + excl;
  if (base + incl >= K && cum < K) {
    unsigned acc = cum;
    for (int k = 0; k < chunk; ++k) {
      unsigned h = hist[hi - k];
      if (acc + h >= K) { *s_b = hi - k; *s_cnt = acc; break; }
      acc += h;
    }
  }
  __syncthreads();
}

// -------- row stats + normalization --------
__global__ __launch_bounds__(256) void k_rowstats(
    const float* __restrict__ x, const float* __restrict__ bdec,
    float* __restrict__ xn, float* __restrict__ xnc,
    float* __restrict__ rmean, float* __restrict__ rstd, double* scalD)
{
  __shared__ float red[256];
  const int row = blockIdx.x, t = threadIdx.x;
  const float* xr = x + (size_t)row * DIN;
  float v0 = xr[t], v1 = xr[t + 256], v2 = xr[t + 512];
  float mean = bsumf(v0 + v1 + v2, red) * (1.0f / DIN);
  float d0 = v0 - mean, d1 = v1 - mean, d2 = v2 - mean;
  float var = bsumf(d0 * d0 + d1 * d1 + d2 * d2, red) * (1.0f / (DIN - 1));
  float sd = sqrtf(var);
  float inv = 1.0f / (sd + 1e-5f);
  float n0 = d0 * inv, n1 = d1 * inv, n2 = d2 * inv;
  size_t o = (size_t)row * DIN;
  xn[o + t] = n0; xn[o + t + 256] = n1; xn[o + t + 512] = n2;
  float b0 = bdec[t], b1 = bdec[t + 256], b2 = bdec[t + 512];
  xnc[o + t] = n0 - b0; xnc[o + t + 256] = n1 - b1; xnc[o + t + 512] = n2 - b2;
  if (t == 0) { rmean[row] = mean; rstd[row] = sd; }
  float sxn = bsumf(n0 + n1 + n2, red);
  float ssq = bsumf(n0 * n0 + n1 * n1 + n2 * n2, red);
  float e0 = b0 - n0, e1 = b1 - n1, e2 = b2 - n2;
  float sq0 = bsumf(e0 * e0 + e1 * e1 + e2 * e2, red);
  if (t == 0) {
    atomicAdd(&scalD[1], (double)sxn);
    atomicAdd(&scalD[2], (double)ssq);
    atomicAdd(&scalD[3], (double)sq0);
  }
}

// -------- encode GEMM: acts = relu(xnc @ Wenc), fp32 --------
__global__ __launch_bounds__(256) void k_gemm(const float* __restrict__ A,
                                              const float* __restrict__ Bm,
                                              float* __restrict__ C)
{
  __shared__ float As[8][128];
  __shared__ float Bs[8][128];
  const int tid = threadIdx.x;
  const int bm = blockIdx.y * 128;
  const int bn = blockIdx.x * 128;
  const int tx = tid & 15, ty = tid >> 4;
  const int ar = tid >> 1, ac4 = (tid & 1) * 4;
  const int bkr = tid >> 5, bc4 = (tid & 31) * 4;
  const float* Aptr = A + (size_t)(bm + ar) * DIN + ac4;
  const float* Bptr = Bm + (size_t)bkr * D + bn + bc4;
  float acc[8][8];
#pragma unroll
  for (int i = 0; i < 8; ++i)
#pragma unroll
    for (int j = 0; j < 8; ++j) acc[i][j] = 0.f;

  for (int k0 = 0; k0 < DIN; k0 += 8) {
    float4 av = *(const float4*)(Aptr + k0);
    float4 bv = *(const float4*)(Bptr + (size_t)k0 * D);
    __syncthreads();
    As[ac4 + 0][ar] = av.x; As[ac4 + 1][ar] = av.y;
    As[ac4 + 2][ar] = av.z; As[ac4 + 3][ar] = av.w;
    *(float4*)&Bs[bkr][bc4] = bv;
    __syncthreads();
#pragma unroll
    for (int kk = 0; kk < 8; ++kk) {
      float a[8], b[8];
#pragma unroll
      for (int i = 0; i < 8; ++i) a[i] = As[kk][ty * 8 + i];
#pragma unroll
      for (int j = 0; j < 4; ++j) { b[j] = Bs[kk][tx * 4 + j]; b[4 + j] = Bs[kk][64 + tx * 4 + j]; }
#pragma unroll
      for (int i = 0; i < 8; ++i)
#pragma unroll
        for (int j = 0; j < 8; ++j) acc[i][j] = fmaf(a[i], b[j], acc[i][j]);
    }
  }
#pragma unroll
  for (int i = 0; i < 8; ++i) {
    int row = bm + ty * 8 + i;
    float4 o0, o1;
    o0.x = fmaxf(acc[i][0], 0.f); o0.y = fmaxf(acc[i][1], 0.f);
    o0.z = fmaxf(acc[i][2], 0.f); o0.w = fmaxf(acc[i][3], 0.f);
    o1.x = fmaxf(acc[i][4], 0.f); o1.y = fmaxf(acc[i][5], 0.f);
    o1.z = fmaxf(acc[i][6], 0.f); o1.w = fmaxf(acc[i][7], 0.f);
    *(float4*)&C[(size_t)row * D + bn + tx * 4] = o0;
    *(float4*)&C[(size_t)row * D + bn + 64 + tx * 4] = o1;
  }
}

// -------- global top-k: 3-level radix histogram on positive float bits --------
__global__ __launch_bounds__(256) void k_hist(const float* __restrict__ acts,
                                              const unsigned* __restrict__ scalU,
                                              unsigned* __restrict__ hist, int mode)
{
  __shared__ unsigned lh[2048];
  for (int j = threadIdx.x; j < 2048; j += 256) lh[j] = 0;
  __syncthreads();
  unsigned b1 = scalU[0], b2 = scalU[2];
  int stride = gridDim.x * blockDim.x;
  for (int i = blockIdx.x * blockDim.x + threadIdx.x; i < NDI; i += stride) {
    float v = acts[i];
    if (v <= 0.f) continue;
    unsigned u = __float_as_uint(v);
    if (mode == 0) atomicAdd(&lh[u >> 21], 1u);
    else if (mode == 1) { if ((u >> 21) == b1) atomicAdd(&lh[(u >> 10) & 0x7FFu], 1u); }
    else { if ((u >> 21) == b1 && ((u >> 10) & 0x7FFu) == b2) atomicAdd(&lh[u & 0x3FFu], 1u); }
  }
  __syncthreads();
  for (int j = threadIdx.x; j < 2048; j += 256) { unsigned c = lh[j]; if (c) atomicAdd(&hist[j], c); }
}

__global__ __launch_bounds__(256) void k_scan(unsigned* scalU, const unsigned* __restrict__ hist,
                                              int nb, int mode)
{
  __shared__ unsigned sscan[256];
  __shared__ int s_b; __shared__ unsigned s_cnt;
  if (threadIdx.x == 0) { s_b = 0; s_cnt = 0; }
  __syncthreads();
  unsigned base = (mode == 0) ? 0u : (mode == 1 ? scalU[1] : scalU[3]);
  findBin(hist, nb, TOPK_TOTAL, base, sscan, &s_b, &s_cnt);
  if (threadIdx.x == 0) {
    if (mode == 0) { scalU[0] = (unsigned)s_b; scalU[1] = s_cnt; }
    else if (mode == 1) { scalU[2] = (unsigned)s_b; scalU[3] = s_cnt; }
    else {
      unsigned cut = (scalU[0] << 21) | (scalU[2] << 10) | (unsigned)s_b;
      scalU[4] = cut; scalU[5] = s_cnt; scalU[6] = TOPK_TOTAL - s_cnt;
    }
  }
}

__global__ __launch_bounds__(256) void k_tiecollect(const float* __restrict__ acts,
                                                    unsigned* scalU, unsigned* tieIdx)
{
  unsigned cut = scalU[4];
  int stride = gridDim.x * blockDim.x;
  for (int i = blockIdx.x * blockDim.x + threadIdx.x; i < NDI; i += stride) {
    float v = acts[i];
    if (v > 0.f && __float_as_uint(v) == cut) {
      unsigned p = atomicAdd(&scalU[8], 1u);
      if (p < TIECAP) tieIdx[p] = (unsigned)i;
    }
  }
}

__global__ __launch_bounds__(256) void k_tieresolve(unsigned* scalU, const unsigned* __restrict__ tieIdx)
{
  __shared__ unsigned tbuf[TIECAP];
  __shared__ int sthr;
  int t = threadIdx.x;
  int n = (int)scalU[8]; if (n > TIECAP) n = TIECAP;
  int need = (int)scalU[6];
  for (int j = t; j < n; j += 256) tbuf[j] = tieIdx[j];
  if (t == 0) sthr = 0x7FFFFFFF;
  __syncthreads();
  if (need < n) {
    for (int ci = t; ci < n; ci += 256) {
      unsigned me = tbuf[ci];
      int r = 0;
      for (int j = 0; j < n; ++j) r += (tbuf[j] < me) ? 1 : 0;
      if (r == need - 1) sthr = (int)me;   // unique writer (indices distinct)
    }
  }
  __syncthreads();
  if (t == 0) scalU[7] = (unsigned)sthr;
}

// -------- selection pass: per-row lists, col flags, l1/l0 --------
__global__ __launch_bounds__(256) void k_s1(const float* __restrict__ acts,
    const unsigned* __restrict__ scalUc, unsigned* rowCnt, unsigned* rlc, float* rlv,
    unsigned* colAct, double* scalD, unsigned* scalU)
{
  __shared__ float redf[256];
  __shared__ unsigned redu[256];
  unsigned cut = scalUc[4]; int tthr = (int)scalUc[7];
  float l1 = 0.f; unsigned l0 = 0;
  int stride = gridDim.x * blockDim.x;
  for (int i = blockIdx.x * blockDim.x + threadIdx.x; i < NDI; i += stride) {
    float v = acts[i];
    if (v <= 0.f) continue;
    unsigned u = __float_as_uint(v);
    if (u > cut || (u == cut && i <= tthr)) {
      int row = i >> 15, col = i & (D - 1);
      unsigned slot = atomicAdd(&rowCnt[row], 1u);
      if (slot < ROWCAP) {
        rlc[(size_t)row * ROWCAP + slot] = (unsigned)col;
        rlv[(size_t)row * ROWCAP + slot] = v;
      }
      colAct[col] = 1u;
      l1 += v; l0++;
    }
  }
  float l1s = bsumf(l1, redf);
  unsigned l0s = bsumu(l0, redu);
  if (threadIdx.x == 0) { atomicAdd(&scalD[0], (double)l1s); atomicAdd(&scalU[9], l0s); }
}

// -------- ordered dead-column compaction + num_dead_features --------
__global__ __launch_bounds__(256) void k_dead(const unsigned* __restrict__ colAct,
    const float* __restrict__ nbna, unsigned* deadCols, unsigned* scalU)
{
  __shared__ unsigned pref[256];
  __shared__ unsigned sbase, svd;
  int t = threadIdx.x;
  if (t == 0) { sbase = 0; svd = 0; }
  __syncthreads();
  for (int c0 = 0; c0 < D; c0 += 256) {
    int c = c0 + t;
    bool act = colAct[c] != 0;
    float f = nbna[c] + 1.0f;
    unsigned isD = (!act && f >= 5.0f) ? 1u : 0u;
    unsigned isV = (!act && f > 5.0f) ? 1u : 0u;
    pref[t] = isD; __syncthreads();
    for (int o = 1; o < 256; o <<= 1) {
      unsigned xx = (t >= o) ? pref[t - o] : 0u; __syncthreads();
      pref[t] += xx; __syncthreads();
    }
    if (isD) deadCols[sbase + pref[t] - 1] = (unsigned)c;
    if (isV) atomicAdd(&svd, 1u);
    __syncthreads();
    if (t == 255) sbase += pref[255];
    __syncthreads();
  }
  if (t == 0) { scalU[10] = sbase; scalU[11] = svd; }
}

// -------- per-row aux top-512 over dead columns (exact, index tie-break) --------
DEVFN float getV(const float* vals, const float* arow, const unsigned* deadCols, int j) {
  return (j < DCAP) ? vals[j] : arow[deadCols[j]];
}

__global__ __launch_bounds__(256) void k_auxsel(const float* __restrict__ acts,
    const unsigned* __restrict__ scalU, const unsigned* __restrict__ deadCols,
    unsigned* auxC, float* auxV, unsigned* auxN)
{
  __shared__ float vals[DCAP];
  __shared__ unsigned hist[2048];
  __shared__ unsigned sscan[256];
  __shared__ int s_b; __shared__ unsigned s_cnt;
  __shared__ unsigned s_sel;
  const int row = blockIdx.x, t = threadIdx.x;
  const int nd = (int)scalU[10];
  const float* arow = acts + (size_t)row * D;
  const int ndc = nd < DCAP ? nd : DCAP;
  for (int j = t; j < ndc; j += 256) vals[j] = arow[deadCols[j]];
  if (t == 0) { s_sel = 0; s_b = 0; s_cnt = 0; }
  __syncthreads();
  unsigned p = 0;
  for (int j = t; j < nd; j += 256) p += (getV(vals, arow, deadCols, j) > 0.f);
  unsigned P = bsumu(p, sscan);
  unsigned* outC = auxC + (size_t)row * TOPK_AUX;
  float* outV = auxV + (size_t)row * TOPK_AUX;
  if (P <= (unsigned)TOPK_AUX) {
    // all positive dead entries selected; zero-valued slots are no-ops downstream
    for (int j = t; j < nd; j += 256) {
      float v = getV(vals, arow, deadCols, j);
      if (v > 0.f) { unsigned s = atomicAdd(&s_sel, 1u); outC[s] = deadCols[j]; outV[s] = v; }
    }
    __syncthreads();
    if (t == 0) auxN[row] = s_sel;
    return;
  }
  // radix refine (11 + 11 + 10 bits) over positive values
  for (int j = t; j < 2048; j += 256) hist[j] = 0;
  __syncthreads();
  for (int j = t; j < nd; j += 256) {
    float v = getV(vals, arow, deadCols, j);
    if (v > 0.f) atomicAdd(&hist[__float_as_uint(v) >> 21], 1u);
  }
  __syncthreads();
  findBin(hist, 2048, (unsigned)TOPK_AUX, 0u, sscan, &s_b, &s_cnt);
  unsigned b1 = (unsigned)s_b, cg1 = s_cnt;
  for (int j = t; j < 2048; j += 256) hist[j] = 0;
  __syncthreads();
  for (int j = t; j < nd; j += 256) {
    float v = getV(vals, arow, deadCols, j);
    if (v > 0.f) { unsigned u = __float_as_uint(v); if ((u >> 21) == b1) atomicAdd(&hist[(u >> 10) & 0x7FFu], 1u); }
  }
  __syncthreads();
  findBin(hist, 2048, (unsigned)TOPK_AUX, cg1, sscan, &s_b, &s_cnt);
  unsigned b2 = (unsigned)s_b, cg2 = s_cnt;
  for (int j = t; j < 1024; j += 256) hist[j] = 0;
  __syncthreads();
  for (int j = t; j < nd; j += 256) {
    float v = getV(vals, arow, deadCols, j);
    if (v > 0.f) {
      unsigned u = __float_as_uint(v);
      if ((u >> 21) == b1 && ((u >> 10) & 0x7FFu) == b2) atomicAdd(&hist[u & 0x3FFu], 1u);
    }
  }
  __syncthreads();
  findBin(hist, 1024, (unsigned)TOPK_AUX, cg2, sscan, &s_b, &s_cnt);
  unsigned cut = (b1 << 21) | (b2 << 10) | (unsigned)s_b;
  int need = TOPK_AUX - (int)s_cnt;
  for (int j = t; j < nd; j += 256) {
    float v = getV(vals, arow, deadCols, j);
    if (v <= 0.f) continue;
    unsigned u = __float_as_uint(v);
    if (u > cut) { unsigned s = atomicAdd(&s_sel, 1u); outC[s] = deadCols[j]; outV[s] = v; }
    else if (u == cut) {
      int r = 0;
      for (int j2 = 0; j2 < j; ++j2) {
        float v2 = getV(vals, arow, deadCols, j2);
        if (v2 > 0.f && __float_as_uint(v2) == cut) r++;
      }
      if (r < need) { unsigned s = atomicAdd(&s_sel, 1u); outC[s] = deadCols[j]; outV[s] = v; }
    }
  }
  __syncthreads();
  if (t == 0) auxN[row] = s_sel;
}

// -------- in-place acts -> acts_topk --------
__global__ __launch_bounds__(256) void k_s2(float* acts, const unsigned* __restrict__ scalU)
{
  unsigned cut = scalU[4]; int tthr = (int)scalU[7];
  int stride = gridDim.x * blockDim.x;
  for (int i = blockIdx.x * blockDim.x + threadIdx.x; i < NDI; i += stride) {
    float v = acts[i];
    unsigned u = __float_as_uint(v);
    bool sel = (v > 0.f) && (u > cut || (u == cut && i <= tthr));
    acts[i] = sel ? v : 0.f;
  }
}

// -------- sparse matryoshka decode + per-group MSE + sae_out + residual --------
__global__ __launch_bounds__(256) void k_decode(const float* __restrict__ Wdec,
    const float* __restrict__ bdec, const float* __restrict__ xn,
    const unsigned* __restrict__ rowCnt, const unsigned* __restrict__ rlc,
    const float* __restrict__ rlv, const float* __restrict__ rmean,
    const float* __restrict__ rstd, float* __restrict__ sae,
    float* __restrict__ resid, double* scalD)
{
  __shared__ int lc[ROWCAP]; __shared__ float lv[ROWCAP];
  __shared__ float red[256];
  const int row = blockIdx.x, t = threadIdx.x;
  int cnt = (int)rowCnt[row]; if (cnt > ROWCAP) cnt = ROWCAP;
  for (int e = t; e < cnt; e += 256) {
    lc[e] = (int)rlc[(size_t)row * ROWCAP + e];
    lv[e] = rlv[(size_t)row * ROWCAP + e];
  }
  __syncthreads();
  float r0 = bdec[t], r1 = bdec[t + 256], r2 = bdec[t + 512];
  size_t o = (size_t)row * DIN;
  float x0 = xn[o + t], x1 = xn[o + t + 256], x2 = xn[o + t + 512];
  const int gidx[6] = {0, 2048, 4096, 8192, 16384, 32768};
#pragma unroll
  for (int g = 0; g < 5; ++g) {
    int s = gidx[g], e2 = gidx[g + 1];
    for (int e = 0; e < cnt; ++e) {
      int c = lc[e];
      if (c >= s && c < e2) {
        float v = lv[e];
        const float* w = Wdec + (size_t)c * DIN;
        r0 = fmaf(v, w[t], r0); r1 = fmaf(v, w[t + 256], r1); r2 = fmaf(v, w[t + 512], r2);
      }
    }
    float dd0 = r0 - x0, dd1 = r1 - x1, dd2 = r2 - x2;
    float sq = bsumf(dd0 * dd0 + dd1 * dd1 + dd2 * dd2, red);
    if (t == 0) atomicAdd(&scalD[4 + g], (double)sq);
  }
  float m = rmean[row], sd = rstd[row];
  sae[o + t] = r0 * sd + m; sae[o + t + 256] = r1 * sd + m; sae[o + t + 512] = r2 * sd + m;
  resid[o + t] = x0 - r0; resid[o + t + 256] = x1 - r1; resid[o + t + 512] = x2 - r2;
}

// -------- aux decode + aux MSE --------
__global__ __launch_bounds__(256) void k_auxdec(const float* __restrict__ Wdec,
    const unsigned* __restrict__ auxC, const float* __restrict__ auxV,
    const unsigned* __restrict__ auxN, const float* __restrict__ resid, double* scalD)
{
  __shared__ int lc[TOPK_AUX]; __shared__ float lv[TOPK_AUX];
  __shared__ float red[256];
  const int row = blockIdx.x, t = threadIdx.x;
  int cnt = (int)auxN[row];
  for (int e = t; e < cnt; e += 256) {
    lc[e] = (int)auxC[(size_t)row * TOPK_AUX + e];
    lv[e] = auxV[(size_t)row * TOPK_AUX + e];
  }
  __syncthreads();
  float a0 = 0.f, a1 = 0.f, a2 = 0.f;
  for (int e = 0; e < cnt; ++e) {
    int c = lc[e]; float v = lv[e];
    const float* w = Wdec + (size_t)c * DIN;
    a0 = fmaf(v, w[t], a0); a1 = fmaf(v, w[t + 256], a1); a2 = fmaf(v, w[t + 512], a2);
  }
  size_t o = (size_t)row * DIN;
  float s0 = resid[o + t], s1 = resid[o + t + 256], s2 = resid[o + t + 512];
  float d0 = a0 - s0, d1 = a1 - s1, d2 = a2 - s2;
  float sq = bsumf(d0 * d0 + d1 * d1 + d2 * d2, red);
  float ab = bsumf(fabsf(a0) + fabsf(a1) + fabsf(a2), red);
  if (t == 0) { atomicAdd(&scalD[9], (double)sq); atomicAdd(&scalD[10], (double)ab); }
}

// -------- scalar finalize --------
__global__ void k_final(const unsigned* __restrict__ scalU, const double* __restrict__ scalD,
                        const float* __restrict__ thr, float* __restrict__ out)
{
  if (threadIdx.x != 0 || blockIdx.x != 0) return;
  const double NEL = (double)B * (double)DIN;
  double term0 = scalD[3] / NEL;
  double tot = term0;
  double mn = 1e300, mx = -1e300;
  for (int g = 0; g < 5; ++g) {
    double l2 = scalD[4 + g] / NEL;
    tot += l2;
    mn = l2 < mn ? l2 : mn;
    mx = l2 > mx ? l2 : mx;
  }
  double mean_l2 = tot / 6.0;
  double sum = scalD[1], ssq = scalD[2];
  double xvar = (ssq - sum * sum / NEL) / (NEL - 1.0);
  double fvu = mean_l2 / (xvar + 1e-10);
  double l1n = scalD[0] / (double)B;
  double l1loss = (double)0.0003f * l1n;
  double l0n = (double)scalU[9] / (double)B;
  double auxmse = scalD[9] / NEL;
  double auxloss = (scalD[10] > 0.0) ? 0.03125 * auxmse : 0.0;
  double loss = mean_l2 + l1loss + auxloss;
  float cutv = __uint_as_float(scalU[4]);
  float t0 = thr[0];
  float newthr = (scalU[9] > 0u) ? (0.99f * t0 + 0.01f * cutv) : t0;
  float* s = out + (size_t)B * DIN + (size_t)NDI;
  s[0] = (float)loss;   s[1] = (float)l1loss; s[2] = (float)mean_l2;
  s[3] = (float)mn;     s[4] = (float)mx;     s[5] = (float)l0n;
  s[6] = (float)l1n;    s[7] = (float)auxloss; s[8] = newthr;
  s[9] = (float)fvu;    s[10] = (float)scalU[11];
}

extern "C" void kernel_launch(void* const* d_in, const int* in_sizes, int n_in,
                              void* d_out, int out_size, void* d_ws, size_t ws_size,
                              hipStream_t stream)
{
  (void)in_sizes; (void)n_in; (void)out_size; (void)ws_size;
  const float* x    = (const float*)d_in[0];
  const float* Wenc = (const float*)d_in[1];
  const float* Wdec = (const float*)d_in[2];
  const float* bdec = (const float*)d_in[3];
  const float* nbna = (const float*)d_in[4];
  const float* thr  = (const float*)d_in[5];
  float* out = (float*)d_out;
  char* ws = (char*)d_ws;

  float* sae  = out;
  float* acts = out + (size_t)B * DIN;   // acts lives in the acts_topk output region

  unsigned* hist1 = (unsigned*)(ws + OFF_HIST1);
  unsigned* hist2 = (unsigned*)(ws + OFF_HIST2);
  unsigned* hist3 = (unsigned*)(ws + OFF_HIST3);
  unsigned* scalU = (unsigned*)(ws + OFF_SCALU);
  double*   scalD = (double*)(ws + OFF_SCALD);
  unsigned* rowCnt= (unsigned*)(ws + OFF_ROWCNT);
  unsigned* colAct= (unsigned*)(ws + OFF_COLACT);
  unsigned* auxN  = (unsigned*)(ws + OFF_AUXCNT);
  float* xn   = (float*)(ws + OFF_XN);
  float* xnc  = (float*)(ws + OFF_XNC);
  float* resid= (float*)(ws + OFF_RES);
  float* rmean= (float*)(ws + OFF_RMEAN);
  float* rstd = (float*)(ws + OFF_RSTD);
  unsigned* tieIdx = (unsigned*)(ws + OFF_TIE);
  unsigned* deadC  = (unsigned*)(ws + OFF_DEAD);
  unsigned* rlc = (unsigned*)(ws + OFF_RLC);
  float*    rlv = (float*)(ws + OFF_RLV);
  unsigned* auxC = (unsigned*)(ws + OFF_AXC);
  float*    auxV = (float*)(ws + OFF_AXV);

  hipMemsetAsync(ws, 0, ZERO_BYTES, stream);
  hipLaunchKernelGGL(k_rowstats, dim3(B), dim3(256), 0, stream, x, bdec, xn, xnc, rmean, rstd, scalD);
  hipLaunchKernelGGL(k_gemm, dim3(D / 128, B / 128), dim3(256), 0, stream, xnc, Wenc, acts);
  hipLaunchKernelGGL(k_hist, dim3(2048), dim3(256), 0, stream, acts, scalU, hist1, 0);
  hipLaunchKernelGGL(k_scan, dim3(1), dim3(256), 0, stream, scalU, hist1, 2048, 0);
  hipLaunchKernelGGL(k_hist, dim3(2048), dim3(256), 0, stream, acts, scalU, hist2, 1);
  hipLaunchKernelGGL(k_scan, dim3(1), dim3(256), 0, stream, scalU, hist2, 2048, 1);
  hipLaunchKernelGGL(k_hist, dim3(2048), dim3(256), 0, stream, acts, scalU, hist3, 2);
  hipLaunchKernelGGL(k_scan, dim3(1), dim3(256), 0, stream, scalU, hist3, 1024, 2);
  hipLaunchKernelGGL(k_tiecollect, dim3(2048), dim3(256), 0, stream, acts, scalU, tieIdx);
  hipLaunchKernelGGL(k_tieresolve, dim3(1), dim3(256), 0, stream, scalU, tieIdx);
  hipLaunchKernelGGL(k_s1, dim3(2048), dim3(256), 0, stream, acts, scalU, rowCnt, rlc, rlv, colAct, scalD, scalU);
  hipLaunchKernelGGL(k_dead, dim3(1), dim3(256), 0, stream, colAct, nbna, deadC, scalU);
  hipLaunchKernelGGL(k_auxsel, dim3(B), dim3(256), 0, stream, acts, scalU, deadC, auxC, auxV, auxN);
  hipLaunchKernelGGL(k_s2, dim3(2048), dim3(256), 0, stream, acts, scalU);
  hipLaunchKernelGGL(k_decode, dim3(B), dim3(256), 0, stream, Wdec, bdec, xn, rowCnt, rlc, rlv, rmean, rstd, sae, resid, scalD);
  hipLaunchKernelGGL(k_auxdec, dim3(B), dim3(256), 0, stream, Wdec, auxC, auxV, auxN, resid, scalD);
  hipLaunchKernelGGL(k_final, dim3(1), dim3(64), 0, stream, scalU, scalD, thr, out);
}